// Round 11
// baseline (374.401 us; speedup 1.0000x reference)
//
#include <hip/hip_runtime.h>
#include <hip/hip_cooperative_groups.h>

namespace cg = cooperative_groups;

// Problem constants (from reference)
#define BATCH 2
#define HH 512
#define WW 512
#define NIN 64
#define NOUT 64
#define N_NZ 131072
#define N_MASK 131072
#define NPIX (BATCH * HH * WW)   // 524288
#define PPW 64                   // points per wave in conv kernel
#define MAX_ALIVE N_MASK         // alive pixels <= number of mask points

// d_ws layout (compact path).  All zeroing now done INSIDE front_kernel
// (cooperative): no hipMemsetAsync node at all on this path.
//   [0,256)            int counter
//   [256, +2MB)        float mask[NPIX]
//   [.., +32MB)        float compact[MAX_ALIVE*NOUT]
//   [.., +2MB)         int   slot[NPIX]
#define WS_MASK_OFF   256
#define WS_CMP_OFF    (WS_MASK_OFF + (size_t)NPIX * 4)
#define WS_SLOT_OFF   (WS_CMP_OFF + (size_t)MAX_ALIVE * NOUT * 4)
#define WS_NEED       (WS_SLOT_OFF + (size_t)NPIX * 4)

// ---------------------------------------------------------------------------
// Front kernel (R14, cooperative): fuses {memset, mask_scatter, build_slot3}.
// R13 evidence: fillBufferAligned 79.6us @ 512MiB is the harness poison
// (uncontrollable); the controllable front section was 3 dispatches of
// launch-latency-dominated work.  One cooperative kernel, 512 blocks x 256
// (2 blocks/CU -> co-resident, grid.sync safe):
//   phase 0: zero mask (2MB) + compact (33.5MB) + counter
//   phase 1: mask scatter (1 point/thread)
//   phase 2: block-aggregated scan -> slot ids (ONE counter atomic/block)
// ---------------------------------------------------------------------------
__global__ __launch_bounds__(256) void front_kernel(
        const float* __restrict__ mv,
        const int* __restrict__ midx,
        float* __restrict__ mask,
        int* __restrict__ slot,
        int* __restrict__ counter,
        float4* __restrict__ compactz) {
    cg::grid_group grid = cg::this_grid();
    const int tid = blockIdx.x * 256 + threadIdx.x;   // 0..131071

    // ---- phase 0: zero everything the later phases accumulate into ----
    const float4 z4 = make_float4(0.f, 0.f, 0.f, 0.f);
    reinterpret_cast<float4*>(mask)[tid] = z4;        // 131072 float4 = 2MB
#pragma unroll
    for (int k = 0; k < 16; ++k)                      // 16*131072 float4 = 33.5MB
        compactz[(size_t)k * (N_MASK) + tid] = z4;
    if (tid == 0) *counter = 0;
    grid.sync();

    // ---- phase 1: mask scatter (exactly N_MASK threads) ----
    {
        const int b = midx[tid * 3 + 0];
        const int y = midx[tid * 3 + 1];
        const int x = midx[tid * 3 + 2];
        atomicAdd(&mask[(b * HH + y) * WW + x], mv[tid]);
    }
    grid.sync();

    // ---- phase 2: slot assignment (block-aggregated scan) ----
    const int t = threadIdx.x;
    const float4 m = reinterpret_cast<const float4*>(mask)[tid];
    const int c0 = (m.x != 0.f) + (m.y != 0.f) + (m.z != 0.f) + (m.w != 0.f);

    const int lane = t & 63;
    const int wv = t >> 6;
    int pre = c0;
#pragma unroll
    for (int d = 1; d < 64; d <<= 1) {
        int tt = __shfl_up(pre, d);
        if (lane >= d) pre += tt;
    }

    __shared__ int wsum[4];
    __shared__ int wbase[4];
    __shared__ int blockbase;
    if (lane == 63) wsum[wv] = pre;
    __syncthreads();
    if (t == 0) {
        int s = 0;
#pragma unroll
        for (int w = 0; w < 4; ++w) { wbase[w] = s; s += wsum[w]; }
        blockbase = atomicAdd(counter, s);      // ONE atomic per block
    }
    __syncthreads();

    int s0 = blockbase + wbase[wv] + (pre - c0);  // exclusive prefix
    int4 sv;
    sv.x = (m.x != 0.f) ? s0++ : -1;
    sv.y = (m.y != 0.f) ? s0++ : -1;
    sv.z = (m.z != 0.f) ? s0++ : -1;
    sv.w = (m.w != 0.f) ? s0++ : -1;
    reinterpret_cast<int4*>(slot)[tid] = sv;
}

// ---------------------------------------------------------------------------
// Conv scatter v6 (FROZEN — R11-measured 80us; model: 17 LDS instrs/dot x
// ~11.5cyc = 192cyc/dot, LDS-issue-bound.  v7's scalar hybrid regressed:
// s_load/ds_read share lgkmcnt -> serialized.  Next lever would be MFMA.)
// ---------------------------------------------------------------------------
__global__ __launch_bounds__(256, 2) void conv_scatter6_kernel(
        const float* __restrict__ values,   // (N_NZ, NIN)
        const float* __restrict__ kern,     // (3,3,NIN,NOUT)
        const int* __restrict__ idx,        // (N_NZ,3) int32
        const int* __restrict__ slot,       // (NPIX,) slot id or -1
        float* __restrict__ compact) {      // (MAX_ALIVE, NOUT) zeroed
    const int wv   = threadIdx.x >> 6;              // wave in block
    const int wg   = blockIdx.x * 4 + wv;           // global wave id
    const int tap  = wg % 9;                        // 9 taps of a tile adjacent
    const int tile = wg / 9;                        // -> values rows L2-hot
    const int lane = threadIdx.x & 63;
    const int ky = tap / 3;
    const int kx = tap % 3;

    // Wave-private row staging: [wave][parity][chain][elem] = 8KB/block.
    __shared__ __align__(16) float rows[4][2][4][NIN];

    // This tap's 64x64 kernel slice -> 64 regs (lane = output channel).
    float kreg[NIN];
    const float* kp = kern + (size_t)tap * NIN * NOUT + lane;
#pragma unroll
    for (int i = 0; i < NIN; ++i) kreg[i] = kp[(size_t)i * NOUT];
    // Pin: forbid rematerialization (R5 evidence: remat re-read 16KB/wave).
#pragma unroll
    for (int i = 0; i < NIN; ++i) asm volatile("" : "+v"(kreg[i]));

    // Lane-parallel probe of 64 points' destinations.
    const int p0 = tile * PPW;
    const int p  = p0 + lane;
    const int b = idx[p * 3 + 0];
    const int y = idx[p * 3 + 1];
    const int x = idx[p * 3 + 2];
    const int sy = min(max(y + ky - 1, 0), HH - 1);
    const int sx = min(max(x + kx - 1, 0), WW - 1);
    const int pix = (b * HH + sy) * WW + sx;
    const int s = slot[pix];

    unsigned long long mrem = __ballot(s >= 0);
    int cnt = __popcll(mrem);                       // uniform

    int J0 = 0, J1 = 0, J2 = 0, J3 = 0;
    float c0 = 0.f, c1 = 0.f, c2 = 0.f, c3 = 0.f;
    if (cnt >= 4) {                                 // prologue: prefetch g1
        J0 = __ffsll((long long)mrem) - 1; mrem &= mrem - 1;
        J1 = __ffsll((long long)mrem) - 1; mrem &= mrem - 1;
        J2 = __ffsll((long long)mrem) - 1; mrem &= mrem - 1;
        J3 = __ffsll((long long)mrem) - 1; mrem &= mrem - 1;
        c0 = values[(size_t)(p0 + J0) * NIN + lane];   // coalesced 256B
        c1 = values[(size_t)(p0 + J1) * NIN + lane];
        c2 = values[(size_t)(p0 + J2) * NIN + lane];
        c3 = values[(size_t)(p0 + J3) * NIN + lane];
    }
    int pc = 0;
    while (cnt >= 4) {
        cnt -= 4;
        // Current group's slots (J* captured before the prefetch pops).
        const int s0 = __shfl(s, J0);
        const int s1 = __shfl(s, J1);
        const int s2 = __shfl(s, J2);
        const int s3 = __shfl(s, J3);
        // Stage current rows to LDS (waits vmcnt for the loads).
        float* rw = &rows[wv][pc][0][0];
        rw[0 * NIN + lane] = c0;
        rw[1 * NIN + lane] = c1;
        rw[2 * NIN + lane] = c2;
        rw[3 * NIN + lane] = c3;
        // Prefetch next group's rows (latency hides under fmacs below).
        float n0 = 0.f, n1 = 0.f, n2 = 0.f, n3 = 0.f;
        if (cnt >= 4) {
            J0 = __ffsll((long long)mrem) - 1; mrem &= mrem - 1;
            J1 = __ffsll((long long)mrem) - 1; mrem &= mrem - 1;
            J2 = __ffsll((long long)mrem) - 1; mrem &= mrem - 1;
            J3 = __ffsll((long long)mrem) - 1; mrem &= mrem - 1;
            n0 = values[(size_t)(p0 + J0) * NIN + lane];
            n1 = values[(size_t)(p0 + J1) * NIN + lane];
            n2 = values[(size_t)(p0 + J2) * NIN + lane];
            n3 = values[(size_t)(p0 + J3) * NIN + lane];
        }
        // Broadcast ds_read_b128 (uniform addr, conflict-free) + 4 chains.
        const float4* q0 = reinterpret_cast<const float4*>(rw + 0 * NIN);
        const float4* q1 = reinterpret_cast<const float4*>(rw + 1 * NIN);
        const float4* q2 = reinterpret_cast<const float4*>(rw + 2 * NIN);
        const float4* q3 = reinterpret_cast<const float4*>(rw + 3 * NIN);
        float a0 = 0.f, a1 = 0.f, a2 = 0.f, a3 = 0.f;
#pragma unroll
        for (int i4 = 0; i4 < 16; ++i4) {
            const float4 w0 = q0[i4];
            const float4 w1 = q1[i4];
            const float4 w2 = q2[i4];
            const float4 w3 = q3[i4];
            a0 = fmaf(w0.x, kreg[4 * i4 + 0], a0);
            a0 = fmaf(w0.y, kreg[4 * i4 + 1], a0);
            a0 = fmaf(w0.z, kreg[4 * i4 + 2], a0);
            a0 = fmaf(w0.w, kreg[4 * i4 + 3], a0);
            a1 = fmaf(w1.x, kreg[4 * i4 + 0], a1);
            a1 = fmaf(w1.y, kreg[4 * i4 + 1], a1);
            a1 = fmaf(w1.z, kreg[4 * i4 + 2], a1);
            a1 = fmaf(w1.w, kreg[4 * i4 + 3], a1);
            a2 = fmaf(w2.x, kreg[4 * i4 + 0], a2);
            a2 = fmaf(w2.y, kreg[4 * i4 + 1], a2);
            a2 = fmaf(w2.z, kreg[4 * i4 + 2], a2);
            a2 = fmaf(w2.w, kreg[4 * i4 + 3], a2);
            a3 = fmaf(w3.x, kreg[4 * i4 + 0], a3);
            a3 = fmaf(w3.y, kreg[4 * i4 + 1], a3);
            a3 = fmaf(w3.z, kreg[4 * i4 + 2], a3);
            a3 = fmaf(w3.w, kreg[4 * i4 + 3], a3);
        }
        atomicAdd(&compact[(size_t)s0 * NOUT + lane], a0);
        atomicAdd(&compact[(size_t)s1 * NOUT + lane], a1);
        atomicAdd(&compact[(size_t)s2 * NOUT + lane], a2);
        atomicAdd(&compact[(size_t)s3 * NOUT + lane], a3);
        c0 = n0; c1 = n1; c2 = n2; c3 = n3;     // rotate prefetched rows
        pc ^= 1;
    }
    // Remainder (<=3 dots): simple path.
    while (mrem) {
        const int j = __ffsll((long long)mrem) - 1; mrem &= mrem - 1;
        const int sj = __shfl(s, j);
        const float* vp = values + (size_t)(p0 + j) * NIN;
        float a = 0.f;
#pragma unroll
        for (int i = 0; i < NIN; ++i) a = fmaf(vp[i], kreg[i], a);
        atomicAdd(&compact[(size_t)sj * NOUT + lane], a);
    }
}

// ---------------------------------------------------------------------------
// Streaming finalize: writes EVERY output element exactly once.
//   dead pixel  -> 0 ; alive -> (compact[slot] + m*bias) * m
// ---------------------------------------------------------------------------
__global__ void finalize2_kernel(float* __restrict__ out,
                                 const float* __restrict__ mask,
                                 const int* __restrict__ slot,
                                 const float* __restrict__ compact,
                                 const float* __restrict__ bias) {
    const int t = blockIdx.x * blockDim.x + threadIdx.x;
    const int p = t >> 4;
    const int c4 = (t & 15) * 4;
    if (p >= NPIX) return;
    float4* o = reinterpret_cast<float4*>(out + (size_t)p * NOUT + c4);
    const int s = slot[p];
    if (s < 0) {
        *o = make_float4(0.f, 0.f, 0.f, 0.f);
        return;
    }
    const float m = mask[p];
    const float4 bb = *reinterpret_cast<const float4*>(bias + c4);
    float4 v = *reinterpret_cast<const float4*>(compact + (size_t)s * NOUT + c4);
    v.x = (v.x + m * bb.x) * m;
    v.y = (v.y + m * bb.y) * m;
    v.z = (v.z + m * bb.z) * m;
    v.w = (v.w + m * bb.w) * m;
    *o = v;
}

// ======================= Fallback path (R3, proven) ========================
__global__ void mask_scatter_kernel(const float* __restrict__ mv,
                                    const int* __restrict__ midx,
                                    float* __restrict__ mask) {
    int n = blockIdx.x * blockDim.x + threadIdx.x;
    if (n < N_MASK) {
        int b = midx[n * 3 + 0];
        int y = midx[n * 3 + 1];
        int x = midx[n * 3 + 2];
        atomicAdd(&mask[(b * HH + y) * WW + x], mv[n]);
    }
}

__global__ __launch_bounds__(64, 2) void conv_scatter_kernel(
        const float* __restrict__ values,
        const float* __restrict__ kern,
        const int* __restrict__ idx,
        const float* __restrict__ mask,
        float* __restrict__ dense) {
    const int bid  = blockIdx.x;
    const int tap  = bid % 9;
    const int tile = bid / 9;
    const int lane = threadIdx.x;
    const int ky = tap / 3;
    const int kx = tap % 3;
    float kreg[NIN];
    const float* kp = kern + (size_t)tap * NIN * NOUT + lane;
#pragma unroll
    for (int i = 0; i < NIN; ++i) kreg[i] = kp[(size_t)i * NOUT];
#pragma unroll
    for (int i = 0; i < NIN; ++i) asm volatile("" : "+v"(kreg[i]));
    const int p0 = tile * PPW;
    for (int pp = 0; pp < PPW; ++pp) {
        const int p = p0 + pp;
        const int b = idx[p * 3 + 0];
        const int y = idx[p * 3 + 1];
        const int x = idx[p * 3 + 2];
        const int sy = min(max(y + ky - 1, 0), HH - 1);
        const int sx = min(max(x + kx - 1, 0), WW - 1);
        const size_t pix = ((size_t)b * HH + sy) * WW + sx;
        if (mask[pix] != 0.0f) {
            const float* vp = values + (size_t)p * NIN;
            float acc = 0.0f;
#pragma unroll
            for (int i = 0; i < NIN; ++i) acc = fmaf(vp[i], kreg[i], acc);
            atomicAdd(&dense[pix * NOUT + lane], acc);
        }
    }
}

__global__ void finalize_kernel(float* __restrict__ out,
                                const float* __restrict__ mask,
                                const float* __restrict__ bias) {
    const int t = blockIdx.x * blockDim.x + threadIdx.x;
    const int p = t >> 4;
    const int c4 = (t & 15) * 4;
    if (p >= NPIX) return;
    const float m = mask[p];
    if (m == 0.0f) return;
    float4* o = reinterpret_cast<float4*>(out + (size_t)p * NOUT + c4);
    const float4 bb = *reinterpret_cast<const float4*>(bias + c4);
    float4 v = *o;
    v.x = (v.x + m * bb.x) * m;
    v.y = (v.y + m * bb.y) * m;
    v.z = (v.z + m * bb.z) * m;
    v.w = (v.w + m * bb.w) * m;
    *o = v;
}

extern "C" void kernel_launch(void* const* d_in, const int* in_sizes, int n_in,
                              void* d_out, int out_size, void* d_ws, size_t ws_size,
                              hipStream_t stream) {
    const float* values      = (const float*)d_in[0];
    const float* kern        = (const float*)d_in[1];
    const float* bias        = (const float*)d_in[2];
    const float* mask_values = (const float*)d_in[3];
    const int*   indices     = (const int*)d_in[4];
    const int*   mask_idx    = (const int*)d_in[5];
    float* out = (float*)d_out;

    if (ws_size >= WS_NEED) {
        // ---- compact path ----
        char* ws = (char*)d_ws;
        int*   counter = (int*)ws;
        float* mask    = (float*)(ws + WS_MASK_OFF);
        float* compact = (float*)(ws + WS_CMP_OFF);
        int*   slot    = (int*)(ws + WS_SLOT_OFF);

        // One cooperative kernel replaces {memset, mask_scatter, build_slot3}.
        float4* compact4 = (float4*)compact;
        void* fargs[] = {(void*)&mask_values, (void*)&mask_idx, (void*)&mask,
                         (void*)&slot, (void*)&counter, (void*)&compact4};
        hipLaunchCooperativeKernel((const void*)front_kernel,
                                   dim3(NPIX / 4 / 256), dim3(256),
                                   fargs, 0, stream);

        const int nwaves = 9 * (N_NZ / PPW);        // 18432
        conv_scatter6_kernel<<<nwaves / 4, 256, 0, stream>>>(
            values, kern, indices, slot, compact);

        const int total = NPIX * (NOUT / 4);
        finalize2_kernel<<<(total + 255) / 256, 256, 0, stream>>>(
            out, mask, slot, compact, bias);
    } else {
        // ---- fallback: R3 structure ----
        float* mask = (float*)d_ws;
        hipMemsetAsync(out, 0, (size_t)out_size * sizeof(float), stream);
        hipMemsetAsync(mask, 0, (size_t)NPIX * sizeof(float), stream);
        mask_scatter_kernel<<<(N_MASK + 255) / 256, 256, 0, stream>>>(
            mask_values, mask_idx, mask);
        const int nblocks = 9 * (N_NZ / PPW);
        conv_scatter_kernel<<<nblocks, 64, 0, stream>>>(
            values, kern, indices, mask, out);
        const int total = NPIX * (NOUT / 4);
        finalize_kernel<<<(total + 255) / 256, 256, 0, stream>>>(out, mask, bias);
    }
}

// Round 15
// 248.531 us; speedup vs baseline: 1.5065x; 1.5065x over previous
//
#include <hip/hip_runtime.h>

// Problem constants (from reference)
#define BATCH 2
#define HH 512
#define WW 512
#define NIN 64
#define NOUT 64
#define N_NZ 131072
#define N_MASK 131072
#define NPIX (BATCH * HH * WW)   // 524288
#define PPW 128                  // points per wave in MFMA conv kernel
#define MAX_ALIVE N_MASK

// d_ws layout (compact path) — R13-proven frame.
#define WS_MASK_OFF   256
#define WS_CMP_OFF    (WS_MASK_OFF + (size_t)NPIX * 4)
#define WS_SLOT_OFF   (WS_CMP_OFF + (size_t)MAX_ALIVE * NOUT * 4)
#define WS_NEED       (WS_SLOT_OFF + (size_t)NPIX * 4)
#define WS_MEMSET     WS_CMP_OFF

typedef __attribute__((ext_vector_type(8))) short bf16x8;
typedef __attribute__((ext_vector_type(4))) float f32x4;

// ---------------------------------------------------------------------------
// Mask scatter (R13-proven)
// ---------------------------------------------------------------------------
__global__ void mask_scatter_kernel(const float* __restrict__ mv,
                                    const int* __restrict__ midx,
                                    float* __restrict__ mask) {
    int n = blockIdx.x * blockDim.x + threadIdx.x;
    if (n < N_MASK) {
        int b = midx[n * 3 + 0];
        int y = midx[n * 3 + 1];
        int x = midx[n * 3 + 2];
        atomicAdd(&mask[(b * HH + y) * WW + x], mv[n]);
    }
}

// ---------------------------------------------------------------------------
// Slot assignment + compact zeroing (R13-proven).  R14's cooperative fusion
// REVERTED: 122us vs this trio's ~25us (grid.sync + 512-block fill = 360GB/s).
// ---------------------------------------------------------------------------
__global__ __launch_bounds__(256) void build_slot3_kernel(
        const float* __restrict__ mask,
        int* __restrict__ slot,
        int* __restrict__ counter,
        float4* __restrict__ compactz) {
    const int ztot = MAX_ALIVE * NOUT / 4;
    const float4 z4 = make_float4(0.f, 0.f, 0.f, 0.f);
    for (int z = blockIdx.x * 256 + threadIdx.x; z < ztot; z += 512 * 256)
        compactz[z] = z4;

    const int tid = threadIdx.x;
    const int gid = blockIdx.x * 256 + tid;
    const float4 m = reinterpret_cast<const float4*>(mask)[gid];
    const int c0 = (m.x != 0.f) + (m.y != 0.f) + (m.z != 0.f) + (m.w != 0.f);

    const int lane = tid & 63;
    const int wv = tid >> 6;
    int pre = c0;
#pragma unroll
    for (int d = 1; d < 64; d <<= 1) {
        int t = __shfl_up(pre, d);
        if (lane >= d) pre += t;
    }
    __shared__ int wsum[4];
    __shared__ int wbase[4];
    __shared__ int blockbase;
    if (lane == 63) wsum[wv] = pre;
    __syncthreads();
    if (tid == 0) {
        int s = 0;
#pragma unroll
        for (int w = 0; w < 4; ++w) { wbase[w] = s; s += wsum[w]; }
        blockbase = atomicAdd(counter, s);
    }
    __syncthreads();

    int s0 = blockbase + wbase[wv] + (pre - c0);
    int4 sv;
    sv.x = (m.x != 0.f) ? s0++ : -1;
    sv.y = (m.y != 0.f) ? s0++ : -1;
    sv.z = (m.z != 0.f) ? s0++ : -1;
    sv.w = (m.w != 0.f) ? s0++ : -1;
    reinterpret_cast<int4*>(slot)[gid] = sv;
}

// ---------------------------------------------------------------------------
// Conv scatter v8 (queued since R15; resubmitted — GPU never acquired):
// MFMA with bf16x3 split (fp32-grade accuracy).
// R11/R13 evidence: v6 is LDS-issue-bound (17 LDS instr/dot x ~11.5cyc =
// 192cyc/dot = 80us) because EVERY lane re-reads the whole row through the
// 16B/instr LDS port.  MFMA's matrix engine does that broadcast in HW.
//   wave = (tile of 128 points, tap); batch = 16 alive dots:
//     A (16 dots x 64 ins) staged in LDS as u32(hi16|lo16 bf16), XOR-swizzled
//     B (64 ins x 64 outs, tap slice) in registers as hi/lo bf16 frags
//     C += Ah*Bh + Ah*Bl + Al*Bh   (24 mfma_16x16x32_bf16 per batch)
//   Partial batches padded with dummy rows; atomics exec-masked (r<cb).
//   LDS: 16 writes + 4 reads per batch ~= 1.3 instr/dot (was 17).
// Split error ~2^-16 relative (hi=trunc16(x), lo=trunc16(x-hi), x-hi exact).
// ---------------------------------------------------------------------------
__global__ __launch_bounds__(256, 2) void conv_scatter8_kernel(
        const float* __restrict__ values,   // (N_NZ, NIN)
        const float* __restrict__ kern,     // (3,3,NIN,NOUT)
        const int* __restrict__ idx,        // (N_NZ,3) int32
        const int* __restrict__ slot,       // (NPIX,) slot id or -1
        float* __restrict__ compact) {      // (MAX_ALIVE, NOUT) zeroed
    const int wv   = threadIdx.x >> 6;
    const int wg   = blockIdx.x * 4 + wv;
    const int tap  = wg % 9;                // 9 taps of a tile adjacent -> L2
    const int tile = wg / 9;
    const int lane = threadIdx.x & 63;
    const int ky = tap / 3;
    const int kx = tap % 3;
    const int p0 = tile * PPW;

    // A staging: [wave][parity][16 rows][64 u32] = 32KB/block.
    __shared__ __align__(16) unsigned int abuf[4][2][16][64];

    // ---- probe 128 points (2 groups of 64) ----
    int sA, sB;
    {
        const int pA = p0 + lane;
        const int b = idx[pA * 3 + 0];
        const int y = idx[pA * 3 + 1];
        const int x = idx[pA * 3 + 2];
        const int sy = min(max(y + ky - 1, 0), HH - 1);
        const int sx = min(max(x + kx - 1, 0), WW - 1);
        sA = slot[(b * HH + sy) * WW + sx];
    }
    {
        const int pB = p0 + 64 + lane;
        const int b = idx[pB * 3 + 0];
        const int y = idx[pB * 3 + 1];
        const int x = idx[pB * 3 + 2];
        const int sy = min(max(y + ky - 1, 0), HH - 1);
        const int sx = min(max(x + kx - 1, 0), WW - 1);
        sB = slot[(b * HH + sy) * WW + sx];
    }
    unsigned long long m0 = __ballot(sA >= 0);
    unsigned long long m1 = __ballot(sB >= 0);
    int cnt = __popcll(m0) + __popcll(m1);
    if (cnt == 0) return;

    // ---- B fragments: this tap's 64x64 slice, hi/lo bf16, in registers ----
    // B[k][o]: lane holds k = c*32 + (lane>>4)*8 + j, o = nt*16 + (lane&15).
    bf16x8 bh[2][4], bl[2][4];
#pragma unroll
    for (int c = 0; c < 2; ++c)
#pragma unroll
        for (int nt = 0; nt < 4; ++nt) {
#pragma unroll
            for (int j = 0; j < 8; ++j) {
                const int k = c * 32 + (lane >> 4) * 8 + j;
                const int o = nt * 16 + (lane & 15);
                const float f = kern[(size_t)tap * NIN * NOUT + k * NOUT + o];
                const unsigned xb = __float_as_uint(f);
                const unsigned short hi = (unsigned short)(xb >> 16);
                const float lof = f - __uint_as_float(xb & 0xffff0000u);
                const unsigned short lo =
                    (unsigned short)(__float_as_uint(lof) >> 16);
                bh[c][nt][j] = (short)hi;
                bl[c][nt][j] = (short)lo;
            }
        }

    // ---- pop/load macro: 16 js (dummy 0 when exhausted), pack selectors ----
    unsigned jp[4] = {0, 0, 0, 0}, jpn[4] = {0, 0, 0, 0};
    float rA[16], rB[16];
#pragma unroll
    for (int r = 0; r < 16; ++r) { rA[r] = 0.f; rB[r] = 0.f; }
#define POPBATCH(JP, RV)                                                    \
    do {                                                                    \
        JP[0] = JP[1] = JP[2] = JP[3] = 0;                                  \
        _Pragma("unroll") for (int r = 0; r < 16; ++r) {                    \
            int j = 0;                                                      \
            if (m0) { j = __ffsll((long long)m0) - 1; m0 &= m0 - 1; }       \
            else if (m1) { j = 64 + (__ffsll((long long)m1) - 1);           \
                           m1 &= m1 - 1; }                                  \
            JP[r & 3] |= ((unsigned)j) << ((r >> 2) * 8);                   \
            RV[r] = values[(size_t)(p0 + j) * NIN + lane];                  \
        }                                                                   \
    } while (0)

    POPBATCH(jp, rA);                       // prologue
    int pc = 0;
    int rem = cnt;
    const int row = lane & 15;
    const unsigned swz = (unsigned)((row & 7) << 4);

    while (rem > 0) {
        const int cb = rem < 16 ? rem : 16;
        // ---- stage current 16 rows to LDS (u32 = hi16|lo16) ----
        char* base = (char*)&abuf[wv][pc][0][0];
#pragma unroll
        for (int r = 0; r < 16; ++r) {
            const float x = rA[r];
            const unsigned xb = __float_as_uint(x);
            const float lof = x - __uint_as_float(xb & 0xffff0000u);
            const unsigned packed = (xb >> 16) |
                (__float_as_uint(lof) & 0xffff0000u);
            *(unsigned*)(base + r * 256 +
                         (((unsigned)lane * 4u) ^ (unsigned)((r & 7) << 4))) =
                packed;
        }
        // ---- prefetch next batch's rows (hides under MFMA below) ----
        if (rem > cb) POPBATCH(jpn, rB);

        // ---- A fragments + MFMA ----
        f32x4 acc[4] = {{0.f, 0.f, 0.f, 0.f}, {0.f, 0.f, 0.f, 0.f},
                        {0.f, 0.f, 0.f, 0.f}, {0.f, 0.f, 0.f, 0.f}};
        char* rbase = (char*)&abuf[wv][pc][0][0] + row * 256;
#pragma unroll
        for (int c = 0; c < 2; ++c) {
            const unsigned b0 =
                ((unsigned)(c * 128 + (lane >> 4) * 32)) ^ swz;
            const unsigned b1 =
                ((unsigned)(c * 128 + (lane >> 4) * 32 + 16)) ^ swz;
            const uint4 wlo = *(const uint4*)(rbase + b0);
            const uint4 whi = *(const uint4*)(rbase + b1);
            unsigned w[8] = {wlo.x, wlo.y, wlo.z, wlo.w,
                             whi.x, whi.y, whi.z, whi.w};
            bf16x8 ah, al;
#pragma unroll
            for (int j = 0; j < 8; ++j) {
                ah[j] = (short)(w[j] & 0xffffu);
                al[j] = (short)(w[j] >> 16);
            }
#pragma unroll
            for (int nt = 0; nt < 4; ++nt) {
                acc[nt] = __builtin_amdgcn_mfma_f32_16x16x32_bf16(
                    ah, bh[c][nt], acc[nt], 0, 0, 0);
                acc[nt] = __builtin_amdgcn_mfma_f32_16x16x32_bf16(
                    ah, bl[c][nt], acc[nt], 0, 0, 0);
                acc[nt] = __builtin_amdgcn_mfma_f32_16x16x32_bf16(
                    al, bh[c][nt], acc[nt], 0, 0, 0);
            }
        }

        // ---- scatter C: lane holds D[r=(lane>>4)*4+i][col=lane&15] ----
        int slotv[4], validr[4];
#pragma unroll
        for (int i = 0; i < 4; ++i) {
            const unsigned jsel = (jp[i] >> ((lane >> 4) * 8)) & 0xffu;
            const int vA = __shfl(sA, (int)(jsel & 63u));
            const int vB = __shfl(sB, (int)(jsel & 63u));
            slotv[i] = (jsel < 64u) ? vA : vB;
            validr[i] = ((lane >> 4) * 4 + i) < cb;
        }
#pragma unroll
        for (int nt = 0; nt < 4; ++nt) {
#pragma unroll
            for (int i = 0; i < 4; ++i) {
                if (validr[i])
                    atomicAdd(&compact[(size_t)slotv[i] * NOUT + nt * 16 +
                                       (lane & 15)],
                              acc[nt][i]);
            }
        }

        // rotate
#pragma unroll
        for (int r = 0; r < 16; ++r) rA[r] = rB[r];
#pragma unroll
        for (int i = 0; i < 4; ++i) jp[i] = jpn[i];
        pc ^= 1;
        rem -= cb;
    }
#undef POPBATCH
}

// ---------------------------------------------------------------------------
// Streaming finalize (R13-proven)
// ---------------------------------------------------------------------------
__global__ void finalize2_kernel(float* __restrict__ out,
                                 const float* __restrict__ mask,
                                 const int* __restrict__ slot,
                                 const float* __restrict__ compact,
                                 const float* __restrict__ bias) {
    const int t = blockIdx.x * blockDim.x + threadIdx.x;
    const int p = t >> 4;
    const int c4 = (t & 15) * 4;
    if (p >= NPIX) return;
    float4* o = reinterpret_cast<float4*>(out + (size_t)p * NOUT + c4);
    const int s = slot[p];
    if (s < 0) {
        *o = make_float4(0.f, 0.f, 0.f, 0.f);
        return;
    }
    const float m = mask[p];
    const float4 bb = *reinterpret_cast<const float4*>(bias + c4);
    float4 v = *reinterpret_cast<const float4*>(compact + (size_t)s * NOUT + c4);
    v.x = (v.x + m * bb.x) * m;
    v.y = (v.y + m * bb.y) * m;
    v.z = (v.z + m * bb.z) * m;
    v.w = (v.w + m * bb.w) * m;
    *o = v;
}

// ======================= Fallback path (R3, proven) ========================
__global__ __launch_bounds__(64, 2) void conv_scatter_kernel(
        const float* __restrict__ values,
        const float* __restrict__ kern,
        const int* __restrict__ idx,
        const float* __restrict__ mask,
        float* __restrict__ dense) {
    const int bid  = blockIdx.x;
    const int tap  = bid % 9;
    const int tile = bid / 9;
    const int lane = threadIdx.x;
    const int ky = tap / 3;
    const int kx = tap % 3;
    float kreg[NIN];
    const float* kp = kern + (size_t)tap * NIN * NOUT + lane;
#pragma unroll
    for (int i = 0; i < NIN; ++i) kreg[i] = kp[(size_t)i * NOUT];
#pragma unroll
    for (int i = 0; i < NIN; ++i) asm volatile("" : "+v"(kreg[i]));
    const int p0 = tile * 64;
    for (int pp = 0; pp < 64; ++pp) {
        const int p = p0 + pp;
        const int b = idx[p * 3 + 0];
        const int y = idx[p * 3 + 1];
        const int x = idx[p * 3 + 2];
        const int sy = min(max(y + ky - 1, 0), HH - 1);
        const int sx = min(max(x + kx - 1, 0), WW - 1);
        const size_t pix = ((size_t)b * HH + sy) * WW + sx;
        if (mask[pix] != 0.0f) {
            const float* vp = values + (size_t)p * NIN;
            float acc = 0.0f;
#pragma unroll
            for (int i = 0; i < NIN; ++i) acc = fmaf(vp[i], kreg[i], acc);
            atomicAdd(&dense[pix * NOUT + lane], acc);
        }
    }
}

__global__ void finalize_kernel(float* __restrict__ out,
                                const float* __restrict__ mask,
                                const float* __restrict__ bias) {
    const int t = blockIdx.x * blockDim.x + threadIdx.x;
    const int p = t >> 4;
    const int c4 = (t & 15) * 4;
    if (p >= NPIX) return;
    const float m = mask[p];
    if (m == 0.0f) return;
    float4* o = reinterpret_cast<float4*>(out + (size_t)p * NOUT + c4);
    const float4 bb = *reinterpret_cast<const float4*>(bias + c4);
    float4 v = *o;
    v.x = (v.x + m * bb.x) * m;
    v.y = (v.y + m * bb.y) * m;
    v.z = (v.z + m * bb.z) * m;
    v.w = (v.w + m * bb.w) * m;
    *o = v;
}

extern "C" void kernel_launch(void* const* d_in, const int* in_sizes, int n_in,
                              void* d_out, int out_size, void* d_ws, size_t ws_size,
                              hipStream_t stream) {
    const float* values      = (const float*)d_in[0];
    const float* kern        = (const float*)d_in[1];
    const float* bias        = (const float*)d_in[2];
    const float* mask_values = (const float*)d_in[3];
    const int*   indices     = (const int*)d_in[4];
    const int*   mask_idx    = (const int*)d_in[5];
    float* out = (float*)d_out;

    if (ws_size >= WS_NEED) {
        // ---- compact path (R13 frame + MFMA conv) ----
        char* ws = (char*)d_ws;
        int*   counter = (int*)ws;
        float* mask    = (float*)(ws + WS_MASK_OFF);
        float* compact = (float*)(ws + WS_CMP_OFF);
        int*   slot    = (int*)(ws + WS_SLOT_OFF);

        hipMemsetAsync(ws, 0, WS_MEMSET, stream);  // counter+mask ONLY (2.1MB)

        mask_scatter_kernel<<<(N_MASK + 255) / 256, 256, 0, stream>>>(
            mask_values, mask_idx, mask);
        build_slot3_kernel<<<NPIX / 4 / 256, 256, 0, stream>>>(
            mask, slot, counter, (float4*)compact);

        const int nwaves = 9 * (N_NZ / PPW);        // 9216
        conv_scatter8_kernel<<<nwaves / 4, 256, 0, stream>>>(
            values, kern, indices, slot, compact);

        const int total = NPIX * (NOUT / 4);
        finalize2_kernel<<<(total + 255) / 256, 256, 0, stream>>>(
            out, mask, slot, compact, bias);
    } else {
        // ---- fallback: R3 structure ----
        float* mask = (float*)d_ws;
        hipMemsetAsync(out, 0, (size_t)out_size * sizeof(float), stream);
        hipMemsetAsync(mask, 0, (size_t)NPIX * sizeof(float), stream);
        mask_scatter_kernel<<<(N_MASK + 255) / 256, 256, 0, stream>>>(
            mask_values, mask_idx, mask);
        const int nblocks = 9 * (N_NZ / 64);
        conv_scatter_kernel<<<nblocks, 64, 0, stream>>>(
            values, kern, indices, mask, out);
        const int total = NPIX * (NOUT / 4);
        finalize_kernel<<<(total + 255) / 256, 256, 0, stream>>>(out, mask, bias);
    }
}